// Round 3
// baseline (1457.458 us; speedup 1.0000x reference)
//
#include <hip/hip_runtime.h>

#define NNODES 100000
#define NEDGES 3200000
#define NGRAPH 1000
#define NPG    100
#define H1DIM  64
#define H2DIM  128
#define MDIM   32
#define NCDIM  10

// ws layout (floats): dinv[100000] | a[300000] | aggh[6400000]  = 27.2 MB
#define WS_FLOATS (100000 + 300000 + 6400000)

// ---------------- K1: in-degree histogram over col ----------------
__global__ void k_deg(const int* __restrict__ col, float* __restrict__ deg) {
    int e = blockIdx.x * blockDim.x + threadIdx.x;
    if (e < NEDGES) atomicAdd(&deg[col[e]], 1.0f);
}

// ---------------- K2: dinv = rsqrt(deg + 1)  (self-loop) ----------------
__global__ void k_dinv(float* __restrict__ deg) {
    int i = blockIdx.x * blockDim.x + threadIdx.x;
    if (i < NNODES) deg[i] = rsqrtf(deg[i] + 1.0f);
}

// ---------------- K3: layer-1 aggregation in input space (3 feats) ----------------
__global__ void k_agg1(const int* __restrict__ ei, const float* __restrict__ x,
                       const float* __restrict__ dinv, float* __restrict__ a) {
    int e = blockIdx.x * blockDim.x + threadIdx.x;
    if (e >= NEDGES) return;
    int r = ei[e];
    int c = ei[NEDGES + e];
    float nrm = dinv[r] * dinv[c];
    atomicAdd(&a[c * 3 + 0], nrm * x[r * 3 + 0]);
    atomicAdd(&a[c * 3 + 1], nrm * x[r * 3 + 1]);
    atomicAdd(&a[c * 3 + 2], nrm * x[r * 3 + 2]);
}

// ---------------- K3b: add self-loop term: a[i] += dinv[i]^2 * x[i] ----------------
__global__ void k_self(const float* __restrict__ x, const float* __restrict__ dinv,
                       float* __restrict__ a) {
    int t = blockIdx.x * blockDim.x + threadIdx.x;
    if (t >= NNODES * 3) return;
    int i = t / 3;
    float di = dinv[i];
    a[t] += di * di * x[t];
}

// ---------------- K5: layer-2 aggregation, wave-per-edge, lane = feature ----------
// h1[r][f] = relu(a[r] . W1[:,f] + b1[f]) computed on the fly (a is L2-resident).
__global__ void k_agg2(const int* __restrict__ ei, const float* __restrict__ a,
                       const float* __restrict__ dinv, const float* __restrict__ W1,
                       const float* __restrict__ b1, float* __restrict__ aggh) {
    unsigned t = blockIdx.x * blockDim.x + threadIdx.x;
    unsigned e = t >> 6;
    int f = (int)(t & 63);
    if (e >= NEDGES) return;
    int r = ei[e];
    int c = ei[NEDGES + e];
    float nrm = dinv[r] * dinv[c];
    float a0 = a[r * 3 + 0], a1 = a[r * 3 + 1], a2 = a[r * 3 + 2];
    float h = a0 * W1[0 * 64 + f] + a1 * W1[1 * 64 + f] + a2 * W1[2 * 64 + f] + b1[f];
    h = fmaxf(h, 0.0f);
    atomicAdd(&aggh[c * 64 + f], nrm * h);
}

// ---------------- K6: per-graph fused: L2 matmul + relu + mean-pool + MLP head ------
__global__ __launch_bounds__(128) void k_head(
    const float* __restrict__ aggh, const float* __restrict__ a,
    const float* __restrict__ dinv, const float* __restrict__ mv,
    const float* __restrict__ W1, const float* __restrict__ b1,
    const float* __restrict__ W2, const float* __restrict__ b2,
    const float* __restrict__ Wc1, const float* __restrict__ bc1,
    const float* __restrict__ Wc2, const float* __restrict__ bc2,
    float* __restrict__ out)
{
    __shared__ float W2s[64 * 128];
    __shared__ float row[64];
    __shared__ float z[160];
    __shared__ float zz[64];
    int g = blockIdx.x;
    int t = threadIdx.x;          // 0..127 : t == output feature of layer 2
    for (int k = t; k < 64 * 128; k += 128) W2s[k] = W2[k];
    float bias = b2[t];
    // per-thread W1 column for on-the-fly h1 of the self node (t < 64 only uses it)
    float w10 = 0.f, w11 = 0.f, w12 = 0.f, b1t = 0.f;
    if (t < 64) { w10 = W1[t]; w11 = W1[64 + t]; w12 = W1[128 + t]; b1t = b1[t]; }
    float acc = 0.0f;
    __syncthreads();
    int base = g * NPG;
    for (int n = 0; n < NPG; ++n) {
        int node = base + n;
        if (t < 64) {
            float di = dinv[node];
            float a0 = a[node * 3 + 0], a1 = a[node * 3 + 1], a2 = a[node * 3 + 2];
            float h1v = fmaxf(a0 * w10 + a1 * w11 + a2 * w12 + b1t, 0.0f);
            row[t] = aggh[node * 64 + t] + di * di * h1v;
        }
        __syncthreads();
        float v = bias;
        #pragma unroll
        for (int f = 0; f < 64; ++f) v += row[f] * W2s[f * 128 + t];
        acc += fmaxf(v, 0.0f);
        __syncthreads();
    }
    z[t] = acc * (1.0f / NPG);
    if (t < MDIM) z[H2DIM + t] = mv[g * MDIM + t];
    __syncthreads();
    if (t < 64) {
        float w = bc1[t];
        for (int k = 0; k < 160; ++k) w += z[k] * Wc1[k * 64 + t];
        zz[t] = fmaxf(w, 0.0f);
    }
    __syncthreads();
    if (t < NCDIM) {
        float o = bc2[t];
        #pragma unroll
        for (int k = 0; k < 64; ++k) o += zz[k] * Wc2[k * NCDIM + t];
        out[g * NCDIM + t] = o;
    }
}

extern "C" void kernel_launch(void* const* d_in, const int* in_sizes, int n_in,
                              void* d_out, int out_size, void* d_ws, size_t ws_size,
                              hipStream_t stream) {
    const float* x   = (const float*)d_in[0];
    const int*   ei  = (const int*)d_in[1];   // int64 in reference -> int32 on device
    // d_in[2] = batch (int32) — fixed structure: node i -> graph i/100
    const float* mv  = (const float*)d_in[3];
    const float* W1  = (const float*)d_in[4];
    const float* b1  = (const float*)d_in[5];
    const float* W2  = (const float*)d_in[6];
    const float* b2  = (const float*)d_in[7];
    const float* Wc1 = (const float*)d_in[8];
    const float* bc1 = (const float*)d_in[9];
    const float* Wc2 = (const float*)d_in[10];
    const float* bc2 = (const float*)d_in[11];
    float* out = (float*)d_out;

    if (ws_size < (size_t)WS_FLOATS * sizeof(float)) return;  // clean fail, no fault

    float* ws   = (float*)d_ws;
    float* dinv = ws;                         // 100000 floats (deg -> dinv in place)
    float* a    = ws + 100000;                // 300000 floats
    float* aggh = ws + 400000;                // 6400000 floats

    hipMemsetAsync(dinv, 0, (size_t)NNODES * sizeof(float), stream);
    hipMemsetAsync(a,    0, (size_t)NNODES * 3 * sizeof(float), stream);
    hipMemsetAsync(aggh, 0, (size_t)NNODES * 64 * sizeof(float), stream);

    const int* col = ei + NEDGES;

    k_deg  <<<(NEDGES + 255) / 256, 256, 0, stream>>>(col, dinv);
    k_dinv <<<(NNODES + 255) / 256, 256, 0, stream>>>(dinv);
    k_agg1 <<<(NEDGES + 255) / 256, 256, 0, stream>>>(ei, x, dinv, a);
    k_self <<<(NNODES * 3 + 255) / 256, 256, 0, stream>>>(x, dinv, a);
    {
        long long total = (long long)NEDGES * 64;
        int blocks = (int)((total + 255) / 256);
        k_agg2<<<blocks, 256, 0, stream>>>(ei, a, dinv, W1, b1, aggh);
    }
    k_head<<<NGRAPH, 128, 0, stream>>>(aggh, a, dinv, mv, W1, b1, W2, b2,
                                       Wc1, bc1, Wc2, bc2, out);
}

// Round 4
// 1252.330 us; speedup vs baseline: 1.1638x; 1.1638x over previous
//
#include <hip/hip_runtime.h>

#define NNODES 100000
#define NEDGES 3200000
#define NGRAPH 1000
#define NPG    100
#define MDIM   32
#define NCDIM  10

// ws layout (float units):
//  xd4   @ 0        : 100000 float4  (x0,x1,x2,dinv)      1.6 MB
//  a4    @ 400000   : 100000 float4  (a0,a1,a2,dinv)      1.6 MB
//  cnt   @ 800000   : 100000 int                          0.4 MB
//  rowptr@ 900000   : 100000 int                          0.4 MB
//  cursor@ 1000000  : 100000 int                          0.4 MB
//  slot  @ 1100000  : 3200000 int                         12.8 MB
#define WS_FLOATS 4300000   // 17.2 MB total

// ---------------- K1: in-degree histogram (int atomics) ----------------
__global__ void k_count(const int* __restrict__ col, int* __restrict__ cnt) {
    int e = blockIdx.x * blockDim.x + threadIdx.x;
    if (e < NEDGES) atomicAdd(&cnt[col[e]], 1);
}

// ---------------- K2: single-block scan -> rowptr/cursor, dinv, xd4 ----------------
__global__ __launch_bounds__(1024) void k_scan(const int* __restrict__ cnt,
                                               const float* __restrict__ x,
                                               int* __restrict__ rowptr,
                                               int* __restrict__ cursor,
                                               float4* __restrict__ xd4) {
    __shared__ int sums[1024];
    const int CH = (NNODES + 1023) / 1024;       // 98
    int t = threadIdx.x;
    int lo = t * CH, hi = min(lo + CH, NNODES);
    int s = 0;
    for (int i = lo; i < hi; ++i) s += cnt[i];
    sums[t] = s;
    __syncthreads();
    for (int off = 1; off < 1024; off <<= 1) {
        int v = sums[t];
        int u = (t >= off) ? sums[t - off] : 0;
        __syncthreads();
        sums[t] = v + u;
        __syncthreads();
    }
    int run = (t == 0) ? 0 : sums[t - 1];
    for (int i = lo; i < hi; ++i) {
        rowptr[i] = run; cursor[i] = run;
        int c = cnt[i];
        run += c;
        float di = rsqrtf((float)c + 1.0f);
        xd4[i] = make_float4(x[3 * i], x[3 * i + 1], x[3 * i + 2], di);
    }
}

// ---------------- K3: scatter sources into CSR slots ----------------
__global__ void k_fill(const int* __restrict__ ei, int* __restrict__ cursor,
                       int* __restrict__ slot) {
    int e = blockIdx.x * blockDim.x + threadIdx.x;
    if (e >= NEDGES) return;
    int r = ei[e];
    int c = ei[NEDGES + e];
    slot[atomicAdd(&cursor[c], 1)] = r;
}

// ---------------- K4: a4[i] = (dinv_i * sum_r dinv_r x_r + dinv_i^2 x_i , dinv_i) ----
__global__ void k_a(const int* __restrict__ rowptr, const int* __restrict__ cnt,
                    const int* __restrict__ slot, const float4* __restrict__ xd4,
                    float4* __restrict__ a4) {
    int i = blockIdx.x * blockDim.x + threadIdx.x;
    if (i >= NNODES) return;
    int s = rowptr[i], d = cnt[i];
    float ax = 0.f, ay = 0.f, az = 0.f;
    for (int k = 0; k < d; ++k) {
        int r = slot[s + k];
        float4 xr = xd4[r];
        ax += xr.w * xr.x; ay += xr.w * xr.y; az += xr.w * xr.z;
    }
    float4 xi = xd4[i];
    float di = xi.w;
    a4[i] = make_float4(di * (ax + di * xi.x),
                        di * (ay + di * xi.y),
                        di * (az + di * xi.z), di);
}

// ---------------- K5: fused per-graph: agg2 + W2 matmul + pool + MLP head ----------
__global__ __launch_bounds__(256) void k_fused(
    const int* __restrict__ rowptr, const int* __restrict__ cnt,
    const int* __restrict__ slot, const float4* __restrict__ a4,
    const float* __restrict__ mv,
    const float* __restrict__ W1, const float* __restrict__ b1,
    const float* __restrict__ W2, const float* __restrict__ b2,
    const float* __restrict__ Wc1, const float* __restrict__ bc1,
    const float* __restrict__ Wc2, const float* __restrict__ bc2,
    float* __restrict__ out)
{
    __shared__ float W2s[64 * 128];          // 32 KB
    __shared__ float rowbuf[4][64];
    __shared__ float pools[4 * 128];
    __shared__ float zbuf[160];
    __shared__ float zz[64];

    int g = blockIdx.x;
    int t = threadIdx.x;
    int w = t >> 6;            // wave 0..3
    int lane = t & 63;         // = feature f for phase 1, = j for phase 2

    for (int k = t; k < 64 * 128; k += 256) W2s[k] = W2[k];
    float w10 = W1[lane], w11 = W1[64 + lane], w12 = W1[128 + lane], b1f = b1[lane];
    float b2j0 = b2[lane], b2j1 = b2[64 + lane];
    float pool0 = 0.f, pool1 = 0.f;
    __syncthreads();

    for (int n = w; n < NPG; n += 4) {
        int node = g * NPG + n;
        int s = rowptr[node], d = cnt[node];
        float acc = 0.f;
        for (int base = 0; base < d; base += 64) {
            int m = min(64, d - base);
            int sl = (lane < m) ? slot[s + base + lane] : 0;
            for (int k = 0; k < m; ++k) {
                int r = __shfl(sl, k);
                float4 ar = a4[r];
                float h = fmaxf(ar.x * w10 + ar.y * w11 + ar.z * w12 + b1f, 0.f);
                acc += ar.w * h;
            }
        }
        float4 ai = a4[node];
        float hs = fmaxf(ai.x * w10 + ai.y * w11 + ai.z * w12 + b1f, 0.f);
        rowbuf[w][lane] = ai.w * (acc + ai.w * hs);
        // same-wave LDS write->read: compiler inserts lgkmcnt wait
        float v0 = b2j0, v1 = b2j1;
        #pragma unroll
        for (int f = 0; f < 64; ++f) {
            float rv = rowbuf[w][f];
            v0 += rv * W2s[f * 128 + lane];
            v1 += rv * W2s[f * 128 + 64 + lane];
        }
        pool0 += fmaxf(v0, 0.f);
        pool1 += fmaxf(v1, 0.f);
    }
    pools[w * 128 + lane]      = pool0;
    pools[w * 128 + 64 + lane] = pool1;
    __syncthreads();
    if (t < 128) {
        float z = (pools[t] + pools[128 + t] + pools[256 + t] + pools[384 + t]) * (1.0f / NPG);
        zbuf[t] = z;
    }
    if (t < MDIM) zbuf[128 + t] = mv[g * MDIM + t];
    __syncthreads();
    if (t < 64) {
        float v = bc1[t];
        for (int k = 0; k < 160; ++k) v += zbuf[k] * Wc1[k * 64 + t];
        zz[t] = fmaxf(v, 0.f);
    }
    __syncthreads();
    if (t < NCDIM) {
        float o = bc2[t];
        #pragma unroll
        for (int k = 0; k < 64; ++k) o += zz[k] * Wc2[k * NCDIM + t];
        out[g * NCDIM + t] = o;
    }
}

extern "C" void kernel_launch(void* const* d_in, const int* in_sizes, int n_in,
                              void* d_out, int out_size, void* d_ws, size_t ws_size,
                              hipStream_t stream) {
    const float* x   = (const float*)d_in[0];
    const int*   ei  = (const int*)d_in[1];   // int64 in ref -> int32 on device
    const float* mv  = (const float*)d_in[3];
    const float* W1  = (const float*)d_in[4];
    const float* b1  = (const float*)d_in[5];
    const float* W2  = (const float*)d_in[6];
    const float* b2  = (const float*)d_in[7];
    const float* Wc1 = (const float*)d_in[8];
    const float* bc1 = (const float*)d_in[9];
    const float* Wc2 = (const float*)d_in[10];
    const float* bc2 = (const float*)d_in[11];
    float* out = (float*)d_out;

    if (ws_size < (size_t)WS_FLOATS * sizeof(float)) return;  // clean fail, no fault

    float*  ws     = (float*)d_ws;
    float4* xd4    = (float4*)(ws);             // 100000 float4
    float4* a4     = (float4*)(ws + 400000);    // 100000 float4
    int*    cnt    = (int*)(ws + 800000);
    int*    rowptr = (int*)(ws + 900000);
    int*    cursor = (int*)(ws + 1000000);
    int*    slot   = (int*)(ws + 1100000);      // 3200000 ints

    hipMemsetAsync(cnt, 0, (size_t)NNODES * sizeof(int), stream);

    const int* col = ei + NEDGES;

    k_count<<<(NEDGES + 255) / 256, 256, 0, stream>>>(col, cnt);
    k_scan <<<1, 1024, 0, stream>>>(cnt, x, rowptr, cursor, xd4);
    k_fill <<<(NEDGES + 255) / 256, 256, 0, stream>>>(ei, cursor, slot);
    k_a    <<<(NNODES + 255) / 256, 256, 0, stream>>>(rowptr, cnt, slot, xd4, a4);
    k_fused<<<NGRAPH, 256, 0, stream>>>(rowptr, cnt, slot, a4, mv,
                                        W1, b1, W2, b2, Wc1, bc1, Wc2, bc2, out);
}

// Round 5
// 800.664 us; speedup vs baseline: 1.8203x; 1.5641x over previous
//
#include <hip/hip_runtime.h>

#define NNODES 100000
#define NEDGES 3200000
#define NGRAPH 1000
#define NPG    100
#define MDIM   32
#define NCDIM  10
#define NB     98          // ceil(NNODES/1024) scan blocks

// ws layout (float units):
//  xd4   @ 0        : 100000 float4  (x0,x1,x2,dinv)      1.6 MB
//  a4    @ 400000   : 100000 float4  (a0,a1,a2,dinv)      1.6 MB
//  cnt   @ 800000   : 100000 int
//  rowptr@ 900000   : 100000 int
//  cursor@ 1000000  : 100000 int
//  bsum  @ 1099000  : 128 int   | boff @ 1099128 : 128 int
//  slot  @ 1100000  : 3200000 int                         12.8 MB
#define WS_FLOATS 4300000   // 17.2 MB total

// ---------------- K1: in-degree histogram (int atomics) ----------------
__global__ void k_count(const int* __restrict__ col, int* __restrict__ cnt) {
    int e = blockIdx.x * blockDim.x + threadIdx.x;
    if (e < NEDGES) atomicAdd(&cnt[col[e]], 1);
}

// ---------------- K2a: per-block sums of cnt ----------------
__global__ __launch_bounds__(1024) void k_bsum(const int* __restrict__ cnt,
                                               int* __restrict__ bsum) {
    __shared__ int wsum[16];
    int b = blockIdx.x, t = threadIdx.x;
    int i = b * 1024 + t;
    int v = (i < NNODES) ? cnt[i] : 0;
    for (int off = 32; off; off >>= 1) v += __shfl_down(v, off);
    if ((t & 63) == 0) wsum[t >> 6] = v;
    __syncthreads();
    if (t < 16) {
        int s = wsum[t];
        for (int off = 8; off; off >>= 1) s += __shfl_down(s, off);
        if (t == 0) bsum[b] = s;
    }
}

// ---------------- K2b: exclusive scan of NB block sums (1 tiny block) ----------------
__global__ void k_bscan(const int* __restrict__ bsum, int* __restrict__ boff) {
    __shared__ int s[128];
    int t = threadIdx.x;
    int v = (t < NB) ? bsum[t] : 0;
    s[t] = v;
    __syncthreads();
    for (int off = 1; off < 128; off <<= 1) {
        int u = (t >= off) ? s[t - off] : 0;
        __syncthreads();
        s[t] += u;
        __syncthreads();
    }
    if (t < NB) boff[t] = s[t] - v;   // exclusive
}

// ---------------- K2c: block-local scan + offsets; also xd4/cursor ----------------
__global__ __launch_bounds__(1024) void k_scan2(const int* __restrict__ cnt,
                                                const int* __restrict__ boff,
                                                const float* __restrict__ x,
                                                int* __restrict__ rowptr,
                                                int* __restrict__ cursor,
                                                float4* __restrict__ xd4) {
    __shared__ int s[1024];
    int b = blockIdx.x, t = threadIdx.x;
    int i = b * 1024 + t;
    int c = (i < NNODES) ? cnt[i] : 0;
    s[t] = c;
    __syncthreads();
    for (int off = 1; off < 1024; off <<= 1) {
        int u = (t >= off) ? s[t - off] : 0;
        __syncthreads();
        s[t] += u;
        __syncthreads();
    }
    if (i < NNODES) {
        int excl = s[t] - c + boff[b];
        rowptr[i] = excl;
        cursor[i] = excl;
        float di = rsqrtf((float)c + 1.0f);
        xd4[i] = make_float4(x[3 * i], x[3 * i + 1], x[3 * i + 2], di);
    }
}

// ---------------- K3: scatter sources into CSR slots ----------------
__global__ void k_fill(const int* __restrict__ ei, int* __restrict__ cursor,
                       int* __restrict__ slot) {
    int e = blockIdx.x * blockDim.x + threadIdx.x;
    if (e >= NEDGES) return;
    int r = ei[e];
    int c = ei[NEDGES + e];
    slot[atomicAdd(&cursor[c], 1)] = r;
}

// ---------------- K4: a4[i] = (dinv_i*(sum_r dinv_r x_r + dinv_i x_i), dinv_i) ------
__global__ void k_a(const int* __restrict__ rowptr, const int* __restrict__ cnt,
                    const int* __restrict__ slot, const float4* __restrict__ xd4,
                    float4* __restrict__ a4) {
    int i = blockIdx.x * blockDim.x + threadIdx.x;
    if (i >= NNODES) return;
    int s = rowptr[i], d = cnt[i];
    float ax = 0.f, ay = 0.f, az = 0.f;
    for (int k = 0; k < d; ++k) {
        int r = slot[s + k];
        float4 xr = xd4[r];
        ax += xr.w * xr.x; ay += xr.w * xr.y; az += xr.w * xr.z;
    }
    float4 xi = xd4[i];
    float di = xi.w;
    a4[i] = make_float4(di * (ax + di * xi.x),
                        di * (ay + di * xi.y),
                        di * (az + di * xi.z), di);
}

// ---------------- K5: fused per-graph: agg2 + W2 matmul + pool + MLP head ----------
__global__ __launch_bounds__(256) void k_fused(
    const int* __restrict__ rowptr, const int* __restrict__ cnt,
    const int* __restrict__ slot, const float4* __restrict__ a4,
    const float* __restrict__ mv,
    const float* __restrict__ W1, const float* __restrict__ b1,
    const float* __restrict__ W2, const float* __restrict__ b2,
    const float* __restrict__ Wc1, const float* __restrict__ bc1,
    const float* __restrict__ Wc2, const float* __restrict__ bc2,
    float* __restrict__ out)
{
    __shared__ float W2s[64 * 128];          // 32 KB
    __shared__ float rowbuf[4][64];
    __shared__ float pools[4 * 128];
    __shared__ float zbuf[160];
    __shared__ float zz[64];

    int g = blockIdx.x;
    int t = threadIdx.x;
    int w = t >> 6;            // wave 0..3
    int lane = t & 63;

    for (int k = t; k < 64 * 128; k += 256) W2s[k] = W2[k];
    float w10 = W1[lane], w11 = W1[64 + lane], w12 = W1[128 + lane], b1f = b1[lane];
    float b2j0 = b2[lane], b2j1 = b2[64 + lane];
    float pool0 = 0.f, pool1 = 0.f;
    __syncthreads();

    for (int n = w; n < NPG; n += 4) {
        int node = g * NPG + n;
        int s = rowptr[node], d = cnt[node];
        float acc = 0.f;
        for (int base = 0; base < d; base += 64) {
            int m = min(64, d - base);
            int sl = (lane < m) ? slot[s + base + lane] : 0;
            for (int k = 0; k < m; ++k) {
                int r = __shfl(sl, k);
                float4 ar = a4[r];
                float h = fmaxf(ar.x * w10 + ar.y * w11 + ar.z * w12 + b1f, 0.f);
                acc += ar.w * h;
            }
        }
        float4 ai = a4[node];
        float hs = fmaxf(ai.x * w10 + ai.y * w11 + ai.z * w12 + b1f, 0.f);
        rowbuf[w][lane] = ai.w * (acc + ai.w * hs);
        float v0 = b2j0, v1 = b2j1;
        #pragma unroll
        for (int f = 0; f < 64; ++f) {
            float rv = rowbuf[w][f];
            v0 += rv * W2s[f * 128 + lane];
            v1 += rv * W2s[f * 128 + 64 + lane];
        }
        pool0 += fmaxf(v0, 0.f);
        pool1 += fmaxf(v1, 0.f);
    }
    pools[w * 128 + lane]      = pool0;
    pools[w * 128 + 64 + lane] = pool1;
    __syncthreads();
    if (t < 128) {
        zbuf[t] = (pools[t] + pools[128 + t] + pools[256 + t] + pools[384 + t]) * (1.0f / NPG);
    }
    if (t < MDIM) zbuf[128 + t] = mv[g * MDIM + t];
    __syncthreads();
    if (t < 64) {
        float v = bc1[t];
        for (int k = 0; k < 160; ++k) v += zbuf[k] * Wc1[k * 64 + t];
        zz[t] = fmaxf(v, 0.f);
    }
    __syncthreads();
    if (t < NCDIM) {
        float o = bc2[t];
        #pragma unroll
        for (int k = 0; k < 64; ++k) o += zz[k] * Wc2[k * NCDIM + t];
        out[g * NCDIM + t] = o;
    }
}

extern "C" void kernel_launch(void* const* d_in, const int* in_sizes, int n_in,
                              void* d_out, int out_size, void* d_ws, size_t ws_size,
                              hipStream_t stream) {
    const float* x   = (const float*)d_in[0];
    const int*   ei  = (const int*)d_in[1];   // int64 in ref -> int32 on device
    const float* mv  = (const float*)d_in[3];
    const float* W1  = (const float*)d_in[4];
    const float* b1  = (const float*)d_in[5];
    const float* W2  = (const float*)d_in[6];
    const float* b2  = (const float*)d_in[7];
    const float* Wc1 = (const float*)d_in[8];
    const float* bc1 = (const float*)d_in[9];
    const float* Wc2 = (const float*)d_in[10];
    const float* bc2 = (const float*)d_in[11];
    float* out = (float*)d_out;

    if (ws_size < (size_t)WS_FLOATS * sizeof(float)) return;  // clean fail, no fault

    float*  ws     = (float*)d_ws;
    float4* xd4    = (float4*)(ws);             // 100000 float4
    float4* a4     = (float4*)(ws + 400000);    // 100000 float4
    int*    cnt    = (int*)(ws + 800000);
    int*    rowptr = (int*)(ws + 900000);
    int*    cursor = (int*)(ws + 1000000);
    int*    bsum   = (int*)(ws + 1099000);      // 128 ints
    int*    boff   = (int*)(ws + 1099128);      // 128 ints
    int*    slot   = (int*)(ws + 1100000);      // 3200000 ints

    hipMemsetAsync(cnt, 0, (size_t)NNODES * sizeof(int), stream);

    const int* col = ei + NEDGES;

    k_count<<<(NEDGES + 255) / 256, 256, 0, stream>>>(col, cnt);
    k_bsum <<<NB, 1024, 0, stream>>>(cnt, bsum);
    k_bscan<<<1, 128, 0, stream>>>(bsum, boff);
    k_scan2<<<NB, 1024, 0, stream>>>(cnt, boff, x, rowptr, cursor, xd4);
    k_fill <<<(NEDGES + 255) / 256, 256, 0, stream>>>(ei, cursor, slot);
    k_a    <<<(NNODES + 255) / 256, 256, 0, stream>>>(rowptr, cnt, slot, xd4, a4);
    k_fused<<<NGRAPH, 256, 0, stream>>>(rowptr, cnt, slot, a4, mv,
                                        W1, b1, W2, b2, Wc1, bc1, Wc2, bc2, out);
}